// Round 9
// baseline (191.620 us; speedup 1.0000x reference)
//
#include <hip/hip_runtime.h>
#include <math.h>

#define N_REF   50000
#define BATCH   16
#define KDIM    4096          // 32*128
#define CHUNK   512           // k-chunk in floats -> 2KB CONTIGUOUS per row per phase
#define NCHUNK  (KDIM / CHUNK) // 8
#define RPB     16            // n-rows per block
#define RPW     4             // n-rows per wave (unique rows -> raw read exactly once)

typedef float f32x4 __attribute__((ext_vector_type(4)));
typedef __attribute__((address_space(3))) uint32_t lds_u32;
typedef const __attribute__((address_space(1))) uint32_t glb_u32;

// K1: dist'[b,n] = r2[n] - 2*dot(x[b], raw[n])   (x2[b] dropped: softmax-invariant)
//
// R8: DRAM-page experiment. R7 (183us) reads 1KB per row per phase; the two
// 1KB halves of a 2KB HBM page land ~2400cy apart with thousands of competing
// streams in between -> double row-activations. CHUNK=512 issues both 1KB
// halves back-to-back (2KB contiguous per row per phase).
// LDS: single 32KB buffer + 2 barriers/phase with COUNTED drain:
//   STAGE (8, oldest) -> LOADRV (8 nontemporal, newest) -> vmcnt(8)+barrier
// drains stage exactly, rv prefetch stays in flight across the barrier.
// VGPR ~116 (acc 64 + rv 32) <= 128 -> 4 waves/SIMD, 4 blocks/CU, LDS 128/160KB.
__global__ __launch_bounds__(256) void dist_kernel(const float* __restrict__ x,
                                                   const float* __restrict__ raw,
                                                   float* __restrict__ dist)
{
    __shared__ float xs[BATCH * CHUNK];      // 32 KiB, single-buffered
    const int tid  = threadIdx.x;
    const int lane = tid & 63;
    const int wv   = tid >> 6;               // 0..3
    const long n_base = (long)blockIdx.x * RPB + (long)wv * RPW;

    float acc[BATCH][RPW];
    #pragma unroll
    for (int b = 0; b < BATCH; ++b)
        #pragma unroll
        for (int r = 0; r < RPW; ++r) acc[b][r] = 0.f;
    float r2a[RPW] = {0.f, 0.f, 0.f, 0.f};
    f32x4 rv[RPW][2];

    // stage x[:, c*512 : c*512+512] -> xs. 32 slots of 1KB; wave wv takes
    // slots {i*4+wv}: LDS dest = uniform base slot*1KB + lane*16 (legal).
#define STAGE(c) do {                                                           \
        _Pragma("unroll")                                                       \
        for (int i_ = 0; i_ < 8; ++i_) {                                        \
            const int s_ = i_ * 4 + wv;                                         \
            const int b_ = s_ >> 1;                                             \
            const int h_ = s_ & 1;                                              \
            const float* g_ = x + (size_t)b_ * KDIM + (size_t)(c) * CHUNK       \
                                + h_ * 256 + lane * 4;                          \
            const float* l_ = &xs[s_ * 256];                                    \
            __builtin_amdgcn_global_load_lds((glb_u32*)g_, (lds_u32*)l_, 16, 0, 0); \
        }                                                                       \
    } while (0)

    // per row: two loads at consecutive 1KB offsets, issued adjacently ->
    // 2KB contiguous request pair hits the same DRAM page back-to-back.
#define LOADRV(c) do {                                                          \
        _Pragma("unroll")                                                       \
        for (int r_ = 0; r_ < RPW; ++r_) {                                      \
            const float* p_ = raw + (size_t)(n_base + r_) * KDIM                \
                                  + (size_t)(c) * CHUNK + lane * 4;             \
            rv[r_][0] = __builtin_nontemporal_load((const f32x4*)(p_));         \
            rv[r_][1] = __builtin_nontemporal_load((const f32x4*)(p_ + 256));   \
        }                                                                       \
    } while (0)

#define COMPUTE() do {                                                          \
        _Pragma("unroll")                                                       \
        for (int r_ = 0; r_ < RPW; ++r_)                                        \
            _Pragma("unroll")                                                   \
            for (int h_ = 0; h_ < 2; ++h_) {                                    \
                r2a[r_] = fmaf(rv[r_][h_].x, rv[r_][h_].x, r2a[r_]);            \
                r2a[r_] = fmaf(rv[r_][h_].y, rv[r_][h_].y, r2a[r_]);            \
                r2a[r_] = fmaf(rv[r_][h_].z, rv[r_][h_].z, r2a[r_]);            \
                r2a[r_] = fmaf(rv[r_][h_].w, rv[r_][h_].w, r2a[r_]);            \
            }                                                                   \
        _Pragma("unroll")                                                       \
        for (int b_ = 0; b_ < BATCH; ++b_) {                                    \
            const f32x4 xv0 = *(const f32x4*)(&xs[b_ * CHUNK + lane * 4]);      \
            const f32x4 xv1 = *(const f32x4*)(&xs[b_ * CHUNK + 256 + lane * 4]);\
            _Pragma("unroll")                                                   \
            for (int r_ = 0; r_ < RPW; ++r_) {                                  \
                acc[b_][r_] = fmaf(rv[r_][0].x, xv0.x, acc[b_][r_]);            \
                acc[b_][r_] = fmaf(rv[r_][0].y, xv0.y, acc[b_][r_]);            \
                acc[b_][r_] = fmaf(rv[r_][0].z, xv0.z, acc[b_][r_]);            \
                acc[b_][r_] = fmaf(rv[r_][0].w, xv0.w, acc[b_][r_]);            \
                acc[b_][r_] = fmaf(rv[r_][1].x, xv1.x, acc[b_][r_]);            \
                acc[b_][r_] = fmaf(rv[r_][1].y, xv1.y, acc[b_][r_]);            \
                acc[b_][r_] = fmaf(rv[r_][1].z, xv1.z, acc[b_][r_]);            \
                acc[b_][r_] = fmaf(rv[r_][1].w, xv1.w, acc[b_][r_]);            \
            }                                                                   \
        }                                                                       \
    } while (0)

    #pragma unroll 1
    for (int c = 0; c < NCHUNK; ++c) {
        // barrier 1: all waves done READING xs (compute's ds_reads are all
        // consumed by FMAs before a wave can reach here) -> safe to restage.
        __builtin_amdgcn_s_barrier();
        __builtin_amdgcn_sched_barrier(0);
        STAGE(c);                 // oldest 8 outstanding
        LOADRV(c);                // newest 8, fly across the barrier
        asm volatile("s_waitcnt vmcnt(8)" ::: "memory");   // drain stage only
        __builtin_amdgcn_s_barrier();
        __builtin_amdgcn_sched_barrier(0);
        COMPUTE();
    }

    // Cross-lane reduce of 64 accumulators: value v = b*4+r ends (summed) on lane v.
    float vals[64];
    #pragma unroll
    for (int b = 0; b < BATCH; ++b)
        #pragma unroll
        for (int r = 0; r < RPW; ++r) vals[b * RPW + r] = acc[b][r];

    #pragma unroll
    for (int k = 0; k < 6; ++k) {
        const int bit = 1 << k;
        const bool hi = (lane & bit) != 0;
        #pragma unroll
        for (int i = 0; i < (64 >> (k + 1)); ++i) {
            const float a  = vals[2 * i];
            const float bb = vals[2 * i + 1];
            const float keep = hi ? bb : a;
            const float send = hi ? a  : bb;
            const float recv = __shfl_xor(send, bit, 64);
            vals[i] = keep + recv;
        }
    }

    // r2: broadcast-reduce the 4 row sums to all lanes
    #pragma unroll
    for (int r = 0; r < RPW; ++r) {
        #pragma unroll
        for (int k = 0; k < 6; ++k)
            r2a[r] += __shfl_xor(r2a[r], 1 << k, 64);
    }

    const int b_out = lane >> 2;
    const int r_out = lane & 3;
    const float r2v = (r_out == 0) ? r2a[0] : (r_out == 1) ? r2a[1]
                    : (r_out == 2) ? r2a[2] : r2a[3];
    dist[(size_t)b_out * N_REF + (size_t)(n_base + r_out)] = r2v - 2.0f * vals[0];
}

// ---------------- softmax: two-stage, full-device ----------------
#define SMB   25      // col-blocks per row
#define SMC   2000    // cols per block (= 500 float4)

__global__ __launch_bounds__(256) void softmax_part(const float* __restrict__ d,
                                                    float2* __restrict__ part)
{
    const int row = blockIdx.y, cb = blockIdx.x;
    const float* p = d + (size_t)row * N_REF + (size_t)cb * SMC;
    const int tid = threadIdx.x;

    float m = -INFINITY, s = 0.f;
    #pragma unroll
    for (int i = 0; i < 2; ++i) {
        const int q = tid + i * 256;          // float4 index within block
        if (q < SMC / 4) {
            const float4 v = *(const float4*)(p + q * 4);
            const float M = fmaxf(m, fmaxf(fmaxf(v.x, v.y), fmaxf(v.z, v.w)));
            s = s * __expf(m - M) + __expf(v.x - M) + __expf(v.y - M)
                                  + __expf(v.z - M) + __expf(v.w - M);
            m = M;
        }
    }
    #pragma unroll
    for (int k = 1; k < 64; k <<= 1) {
        const float mo = __shfl_xor(m, k, 64);
        const float so = __shfl_xor(s, k, 64);
        const float M  = fmaxf(m, mo);
        s = s * __expf(m - M) + so * __expf(mo - M);
        m = M;
    }
    __shared__ float2 wsum[4];
    const int wv = tid >> 6, lane = tid & 63;
    if (lane == 0) wsum[wv] = make_float2(m, s);
    __syncthreads();
    if (tid == 0) {
        float M = wsum[0].x, S = wsum[0].y;
        #pragma unroll
        for (int i = 1; i < 4; ++i) {
            const float M2 = fmaxf(M, wsum[i].x);
            S = S * __expf(M - M2) + wsum[i].y * __expf(wsum[i].x - M2);
            M = M2;
        }
        part[row * SMB + cb] = make_float2(M, S);
    }
}

__global__ __launch_bounds__(256) void softmax_norm(float* __restrict__ d,
                                                    const float2* __restrict__ part)
{
    const int row = blockIdx.y, cb = blockIdx.x;
    const int tid = threadIdx.x;

    // every block redundantly reduces the 25 row-partials (tiny, L2-hit)
    float M = -INFINITY, S = 0.f;
    #pragma unroll
    for (int i = 0; i < SMB; ++i) {
        const float2 ps = part[row * SMB + i];
        const float M2 = fmaxf(M, ps.x);
        S = S * __expf(M - M2) + ps.y * __expf(ps.x - M2);
        M = M2;
    }
    const float Sinv = 1.f / S;

    float* p = d + (size_t)row * N_REF + (size_t)cb * SMC;
    #pragma unroll
    for (int i = 0; i < 2; ++i) {
        const int q = tid + i * 256;
        if (q < SMC / 4) {
            float4 v = *(float4*)(p + q * 4);
            v.x = __expf(v.x - M) * Sinv;
            v.y = __expf(v.y - M) * Sinv;
            v.z = __expf(v.z - M) * Sinv;
            v.w = __expf(v.w - M) * Sinv;
            *(float4*)(p + q * 4) = v;
        }
    }
}

extern "C" void kernel_launch(void* const* d_in, const int* in_sizes, int n_in,
                              void* d_out, int out_size, void* d_ws, size_t ws_size,
                              hipStream_t stream) {
    const float* x   = (const float*)d_in[0];   // [16][32][128]
    const float* raw = (const float*)d_in[1];   // [50000][32][128]
    float* out = (float*)d_out;                 // [16][50000]
    float2* part = (float2*)d_ws;               // 16*25 float2 partials

    dist_kernel<<<N_REF / RPB, 256, 0, stream>>>(x, raw, out);
    softmax_part<<<dim3(SMB, BATCH), 256, 0, stream>>>(out, part);
    softmax_norm<<<dim3(SMB, BATCH), 256, 0, stream>>>(out, part);
}

// Round 10
// 184.948 us; speedup vs baseline: 1.0361x; 1.0361x over previous
//
#include <hip/hip_runtime.h>
#include <math.h>

#define N_REF   50000
#define BATCH   16
#define KDIM    4096          // 32*128
#define CHUNK   256           // k-chunk in floats
#define NCHUNK  (KDIM / CHUNK) // 16
#define RPB     16            // n-rows per block
#define RPW     4             // n-rows per wave (unique rows -> raw read exactly once)

typedef float f32x4 __attribute__((ext_vector_type(4)));
typedef __attribute__((address_space(3))) uint32_t lds_u32;
typedef const __attribute__((address_space(1))) uint32_t glb_u32;

// K1: dist'[b,n] = r2[n] - 2*dot(x[b], raw[n])   (x2[b] dropped: softmax-invariant)
//
// R9 = R7 (183.5us best: LDS-staged x, double buffer, 1 barrier/chunk) with the
// raw stream read at FULL streaming policy: global_load_dwordx4 sc0 nt sc1
// (system scope + nontemporal = no L1/L2 allocation, no MALL allocation).
// R7's nt-only (evict-first, still allocates) gave +4%; this removes the
// 819MB stream's L2 fill/evict work entirely and keeps x pristine in L2.
// asm loads are invisible to compiler waitcnt tracking -> manual discipline:
//   LOADRV (asm, oldest 4) -> STAGE (tracked 4) -> s_waitcnt vmcnt(4)
//   + sched_barrier(0) -> COMPUTE -> __syncthreads (drains vmcnt(0) via stage).
// Ledger: R6 counted-vmcnt null; R8 CHUNK=512 page-contiguity -4% (reverted).
// No min-waves launch bound: R1's (256,3) capped VGPR at 84 -> 1 GB spill.
__global__ __launch_bounds__(256) void dist_kernel(const float* __restrict__ x,
                                                   const float* __restrict__ raw,
                                                   float* __restrict__ dist)
{
    __shared__ float xs[2][BATCH * CHUNK];   // double-buffered, 2 x 16 KiB
    const int tid  = threadIdx.x;
    const int lane = tid & 63;
    const int wv   = tid >> 6;               // 0..3
    const long n_base = (long)blockIdx.x * RPB + (long)wv * RPW;

    float acc[BATCH][RPW];
    #pragma unroll
    for (int b = 0; b < BATCH; ++b)
        #pragma unroll
        for (int r = 0; r < RPW; ++r) acc[b][r] = 0.f;
    float r2a[RPW] = {0.f, 0.f, 0.f, 0.f};
    f32x4 rv[RPW];

#define STAGE(buf, c) do {                                                      \
        _Pragma("unroll")                                                       \
        for (int i_ = 0; i_ < 4; ++i_) {                                        \
            const int b_ = i_ * 4 + wv;                                         \
            const float* g_ = x + (size_t)b_ * KDIM + (size_t)(c) * CHUNK + lane * 4; \
            const float* l_ = &xs[buf][b_ * CHUNK];                             \
            __builtin_amdgcn_global_load_lds((glb_u32*)g_, (lds_u32*)l_, 16, 0, 0); \
        }                                                                       \
    } while (0)

    // streaming-policy raw loads: system scope (sc0 sc1) + nontemporal (nt)
    // -> no L1/L2/MALL allocation for the read-once 819MB stream.
#define LOADRV(c) do {                                                          \
        _Pragma("unroll")                                                       \
        for (int r_ = 0; r_ < RPW; ++r_) {                                      \
            const f32x4* p_ = (const f32x4*)(raw + (size_t)(n_base + r_) * KDIM \
                                   + (size_t)(c) * CHUNK + lane * 4);           \
            asm volatile("global_load_dwordx4 %0, %1, off sc0 nt sc1"           \
                         : "=v"(rv[r_]) : "v"(p_) : "memory");                  \
        }                                                                       \
    } while (0)

#define COMPUTE(buf) do {                                                       \
        _Pragma("unroll")                                                       \
        for (int r_ = 0; r_ < RPW; ++r_) {                                      \
            r2a[r_] = fmaf(rv[r_].x, rv[r_].x, r2a[r_]);                        \
            r2a[r_] = fmaf(rv[r_].y, rv[r_].y, r2a[r_]);                        \
            r2a[r_] = fmaf(rv[r_].z, rv[r_].z, r2a[r_]);                        \
            r2a[r_] = fmaf(rv[r_].w, rv[r_].w, r2a[r_]);                        \
        }                                                                       \
        _Pragma("unroll")                                                       \
        for (int b_ = 0; b_ < BATCH; ++b_) {                                    \
            const f32x4 xv_ = *(const f32x4*)(&xs[buf][b_ * CHUNK + lane * 4]); \
            _Pragma("unroll")                                                   \
            for (int r_ = 0; r_ < RPW; ++r_) {                                  \
                acc[b_][r_] = fmaf(rv[r_].x, xv_.x, acc[b_][r_]);               \
                acc[b_][r_] = fmaf(rv[r_].y, xv_.y, acc[b_][r_]);               \
                acc[b_][r_] = fmaf(rv[r_].z, xv_.z, acc[b_][r_]);               \
                acc[b_][r_] = fmaf(rv[r_].w, xv_.w, acc[b_][r_]);               \
            }                                                                   \
        }                                                                       \
    } while (0)

    // prologue: stage chunk 0, barrier (drains vmcnt -> buffer 0 ready)
    STAGE(0, 0);
    __syncthreads();

    int buf = 0;
    #pragma unroll 1
    for (int c = 0; c < NCHUNK - 1; ++c) {
        LOADRV(c);              // oldest 4 outstanding (asm, untracked)
        STAGE(buf ^ 1, c + 1);  // tracked 4; "memory" clobbers keep order
        asm volatile("s_waitcnt vmcnt(4)" ::: "memory");  // rv done, stage flies
        __builtin_amdgcn_sched_barrier(0);                // no FMA hoist (rule 18)
        COMPUTE(buf);
        __syncthreads();        // compiler drains vmcnt(0) for stage -> all
        buf ^= 1;
    }
    LOADRV(NCHUNK - 1);
    asm volatile("s_waitcnt vmcnt(0)" ::: "memory");
    __builtin_amdgcn_sched_barrier(0);
    COMPUTE(buf);

    // Cross-lane reduce of 64 accumulators: value v = b*4+r ends (summed) on lane v.
    float vals[64];
    #pragma unroll
    for (int b = 0; b < BATCH; ++b)
        #pragma unroll
        for (int r = 0; r < RPW; ++r) vals[b * RPW + r] = acc[b][r];

    #pragma unroll
    for (int k = 0; k < 6; ++k) {
        const int bit = 1 << k;
        const bool hi = (lane & bit) != 0;
        #pragma unroll
        for (int i = 0; i < (64 >> (k + 1)); ++i) {
            const float a  = vals[2 * i];
            const float bb = vals[2 * i + 1];
            const float keep = hi ? bb : a;
            const float send = hi ? a  : bb;
            const float recv = __shfl_xor(send, bit, 64);
            vals[i] = keep + recv;
        }
    }

    // r2: broadcast-reduce the 4 row sums to all lanes
    #pragma unroll
    for (int r = 0; r < RPW; ++r) {
        #pragma unroll
        for (int k = 0; k < 6; ++k)
            r2a[r] += __shfl_xor(r2a[r], 1 << k, 64);
    }

    const int b_out = lane >> 2;
    const int r_out = lane & 3;
    const float r2v = (r_out == 0) ? r2a[0] : (r_out == 1) ? r2a[1]
                    : (r_out == 2) ? r2a[2] : r2a[3];
    dist[(size_t)b_out * N_REF + (size_t)(n_base + r_out)] = r2v - 2.0f * vals[0];
}

// ---------------- softmax: two-stage, full-device ----------------
#define SMB   25      // col-blocks per row
#define SMC   2000    // cols per block (= 500 float4)

__global__ __launch_bounds__(256) void softmax_part(const float* __restrict__ d,
                                                    float2* __restrict__ part)
{
    const int row = blockIdx.y, cb = blockIdx.x;
    const float* p = d + (size_t)row * N_REF + (size_t)cb * SMC;
    const int tid = threadIdx.x;

    float m = -INFINITY, s = 0.f;
    #pragma unroll
    for (int i = 0; i < 2; ++i) {
        const int q = tid + i * 256;          // float4 index within block
        if (q < SMC / 4) {
            const float4 v = *(const float4*)(p + q * 4);
            const float M = fmaxf(m, fmaxf(fmaxf(v.x, v.y), fmaxf(v.z, v.w)));
            s = s * __expf(m - M) + __expf(v.x - M) + __expf(v.y - M)
                                  + __expf(v.z - M) + __expf(v.w - M);
            m = M;
        }
    }
    #pragma unroll
    for (int k = 1; k < 64; k <<= 1) {
        const float mo = __shfl_xor(m, k, 64);
        const float so = __shfl_xor(s, k, 64);
        const float M  = fmaxf(m, mo);
        s = s * __expf(m - M) + so * __expf(mo - M);
        m = M;
    }
    __shared__ float2 wsum[4];
    const int wv = tid >> 6, lane = tid & 63;
    if (lane == 0) wsum[wv] = make_float2(m, s);
    __syncthreads();
    if (tid == 0) {
        float M = wsum[0].x, S = wsum[0].y;
        #pragma unroll
        for (int i = 1; i < 4; ++i) {
            const float M2 = fmaxf(M, wsum[i].x);
            S = S * __expf(M - M2) + wsum[i].y * __expf(wsum[i].x - M2);
            M = M2;
        }
        part[row * SMB + cb] = make_float2(M, S);
    }
}

__global__ __launch_bounds__(256) void softmax_norm(float* __restrict__ d,
                                                    const float2* __restrict__ part)
{
    const int row = blockIdx.y, cb = blockIdx.x;
    const int tid = threadIdx.x;

    // every block redundantly reduces the 25 row-partials (tiny, L2-hit)
    float M = -INFINITY, S = 0.f;
    #pragma unroll
    for (int i = 0; i < SMB; ++i) {
        const float2 ps = part[row * SMB + i];
        const float M2 = fmaxf(M, ps.x);
        S = S * __expf(M - M2) + ps.y * __expf(ps.x - M2);
        M = M2;
    }
    const float Sinv = 1.f / S;

    float* p = d + (size_t)row * N_REF + (size_t)cb * SMC;
    #pragma unroll
    for (int i = 0; i < 2; ++i) {
        const int q = tid + i * 256;
        if (q < SMC / 4) {
            float4 v = *(float4*)(p + q * 4);
            v.x = __expf(v.x - M) * Sinv;
            v.y = __expf(v.y - M) * Sinv;
            v.z = __expf(v.z - M) * Sinv;
            v.w = __expf(v.w - M) * Sinv;
            *(float4*)(p + q * 4) = v;
        }
    }
}

extern "C" void kernel_launch(void* const* d_in, const int* in_sizes, int n_in,
                              void* d_out, int out_size, void* d_ws, size_t ws_size,
                              hipStream_t stream) {
    const float* x   = (const float*)d_in[0];   // [16][32][128]
    const float* raw = (const float*)d_in[1];   // [50000][32][128]
    float* out = (float*)d_out;                 // [16][50000]
    float2* part = (float2*)d_ws;               // 16*25 float2 partials

    dist_kernel<<<N_REF / RPB, 256, 0, stream>>>(x, raw, out);
    softmax_part<<<dim3(SMB, BATCH), 256, 0, stream>>>(out, part);
    softmax_norm<<<dim3(SMB, BATCH), 256, 0, stream>>>(out, part);
}